// Round 2
// baseline (135.917 us; speedup 1.0000x reference)
//
#include <hip/hip_runtime.h>
#include <hip/hip_bf16.h>

typedef __attribute__((ext_vector_type(8))) short short8;   // 8 bf16 (4 VGPRs)
typedef __attribute__((ext_vector_type(4))) float float4v;  // 4 fp32 acc

#define C2EXP 2.8853900817779268f  /* 2*log2(e): exp(2s) = exp2(C2EXP*s), tau=0.5 */

__device__ __forceinline__ float bf16lo(unsigned int u){ return __uint_as_float((u & 0xFFFFu) << 16); }
__device__ __forceinline__ float bf16hi(unsigned int u){ return __uint_as_float(u & 0xFFFF0000u); }

// K1: row-normalize fp32 features (norm clamp @1e-8), cast to bf16, pack 2/lane.
// Also zero the t accumulator (ws is poisoned every launch).
__global__ void k_normalize(const float* __restrict__ f, unsigned int* __restrict__ zb,
                            float* __restrict__ t, int N){
    int lane = threadIdx.x & 63;
    int row  = blockIdx.x * 4 + (threadIdx.x >> 6);
    int gid  = blockIdx.x * 256 + threadIdx.x;
    if (gid < N) t[gid] = 0.0f;
    if (row >= N) return;
    const float2* fr = (const float2*)(f + (size_t)row * 128);
    float2 v = fr[lane];
    float ss = v.x * v.x + v.y * v.y;
    #pragma unroll
    for (int m = 1; m < 64; m <<= 1) ss += __shfl_xor(ss, m);
    float scale = 1.0f / fmaxf(sqrtf(ss), 1e-8f);
    __hip_bfloat16 h0 = __float2bfloat16(v.x * scale);
    __hip_bfloat16 h1 = __float2bfloat16(v.y * scale);
    unsigned short b0, b1;
    __builtin_memcpy(&b0, &h0, 2);
    __builtin_memcpy(&b1, &h1, 2);
    zb[row * 64 + lane] = (unsigned int)b0 | ((unsigned int)b1 << 16);
}

// K1b: group start offsets = exclusive prefix sum of num_crops (one wave, shfl scan)
__global__ void k_offsets(const int* __restrict__ nc, int* __restrict__ offs, int G){
    int lane = threadIdx.x;
    int running = 0;
    for (int base = 0; base < G; base += 64){
        int v = (base + lane < G) ? nc[base + lane] : 0;
        int inc = v;
        #pragma unroll
        for (int d = 1; d < 64; d <<= 1){
            int tt = __shfl_up(inc, d);
            if (lane >= d) inc += tt;
        }
        if (base + lane < G) offs[base + lane] = running + inc - v;
        running += __shfl(inc, 63);
    }
}

// K2: per-group (one wave per group): pos[i] = sum_{j in group, j!=i} exp(2*cos),
// self[i] = exp(2*z_i.z_i).
__global__ void k_pos(const unsigned int* __restrict__ zb, const int* __restrict__ nc,
                      const int* __restrict__ offs, float* __restrict__ possum,
                      float* __restrict__ selfs, int G){
    int g = blockIdx.x, lane = threadIdx.x;
    int st = offs[g];
    int c = nc[g];
    for (int a = 0; a < c; a++){
        unsigned int ua = zb[(st + a) * 64 + lane];
        float a0 = bf16lo(ua), a1 = bf16hi(ua);
        float pacc = 0.0f;
        for (int b = 0; b < c; b++){
            unsigned int ub = zb[(st + b) * 64 + lane];
            float s = a0 * bf16lo(ub) + a1 * bf16hi(ub);
            #pragma unroll
            for (int m = 1; m < 64; m <<= 1) s += __shfl_xor(s, m);
            float e = exp2f(C2EXP * s);
            if (b == a){ if (lane == 0) selfs[st + a] = e; }
            else pacc += e;
        }
        if (lane == 0) possum[st + a] = pacc;
    }
}

// K3: barrier-free Gram row-sums. Each wave owns a 64-row A-slab (full K=128 held as
// MFMA fragments in registers, loaded once) and streams 512 columns of B fragments
// directly from global (Z is 2 MB -> L2-resident). No LDS, no __syncthreads.
// Fragment addressing = the verified LDS pattern, global-addressed:
//   frag(row_base) lane holds z[row_base + (lane&15)][ki*32 + (lane>>4)*8 .. +7]
__global__ __launch_bounds__(256, 2) void k_gram(const unsigned short* __restrict__ z,
                                                 float* __restrict__ t, int N){
    int tid  = threadIdx.x;
    int lane = tid & 63;
    int w    = blockIdx.x * 4 + (tid >> 6);   // global wave id
    int quad = lane >> 4, l15 = lane & 15;
    int chunks = N >> 9;                      // col-chunks of 512
    int rs = w / chunks;                      // 64-row slab index
    int cc = w % chunks;

    // A fragments: 64 rows x full K, 16 x 16B loads, held for the whole kernel
    short8 af[4][4];
    #pragma unroll
    for (int mi = 0; mi < 4; mi++)
        #pragma unroll
        for (int ki = 0; ki < 4; ki++)
            af[mi][ki] = *(const short8*)&z[(size_t)(rs * 64 + mi * 16 + l15) * 128
                                            + ki * 32 + quad * 8];

    float ts[4][4];
    #pragma unroll
    for (int mi = 0; mi < 4; mi++)
        #pragma unroll
        for (int r = 0; r < 4; r++) ts[mi][r] = 0.0f;

    #pragma unroll 1
    for (int jt = 0; jt < 8; jt++){
        int j0 = cc * 512 + jt * 64;
        float4v acc[4][4];
        #pragma unroll
        for (int mi = 0; mi < 4; mi++)
            #pragma unroll
            for (int ni = 0; ni < 4; ni++)
                acc[mi][ni] = (float4v){0.0f, 0.0f, 0.0f, 0.0f};

        #pragma unroll
        for (int ki = 0; ki < 4; ki++){
            short8 bfr[4];
            #pragma unroll
            for (int ni = 0; ni < 4; ni++)
                bfr[ni] = *(const short8*)&z[(size_t)(j0 + ni * 16 + l15) * 128
                                             + ki * 32 + quad * 8];
            #pragma unroll
            for (int mi = 0; mi < 4; mi++)
                #pragma unroll
                for (int ni = 0; ni < 4; ni++)
                    acc[mi][ni] = __builtin_amdgcn_mfma_f32_16x16x32_bf16(
                        af[mi][ki], bfr[ni], acc[mi][ni], 0, 0, 0);
        }
        // Epilogue: e = exp(2s), accumulate row partials.
        // C layout: col = lane&15, row_local = mi*16 + quad*4 + r
        #pragma unroll
        for (int mi = 0; mi < 4; mi++)
            #pragma unroll
            for (int ni = 0; ni < 4; ni++)
                #pragma unroll
                for (int r = 0; r < 4; r++)
                    ts[mi][r] += exp2f(C2EXP * acc[mi][ni][r]);
    }

    // Reduce across the 16 column-lanes (same quad), one atomic per row
    #pragma unroll
    for (int mi = 0; mi < 4; mi++)
        #pragma unroll
        for (int r = 0; r < 4; r++){
            float v = ts[mi][r];
            v += __shfl_xor(v, 1);
            v += __shfl_xor(v, 2);
            v += __shfl_xor(v, 4);
            v += __shfl_xor(v, 8);
            ts[mi][r] = v;
        }
    if (l15 == 0){
        #pragma unroll
        for (int mi = 0; mi < 4; mi++)
            #pragma unroll
            for (int r = 0; r < 4; r++){
                int i = rs * 64 + mi * 16 + quad * 4 + r;
                atomicAdd(&t[i], ts[mi][r]);
            }
    }
}

// K4: loss = mean over rows of log(neg) - log(pos); neg = t - pos - self
__global__ void k_final(const float* __restrict__ t, const float* __restrict__ possum,
                        const float* __restrict__ selfs, float* __restrict__ out, int N){
    int tid = threadIdx.x;
    float s = 0.0f;
    for (int r = tid; r < N; r += 256){
        float p = possum[r];
        float n = t[r] - p - selfs[r];
        s += logf(n) - logf(p);
    }
    #pragma unroll
    for (int m = 1; m < 64; m <<= 1) s += __shfl_xor(s, m);
    __shared__ float red[4];
    if ((tid & 63) == 0) red[tid >> 6] = s;
    __syncthreads();
    if (tid == 0) out[0] = (red[0] + red[1] + red[2] + red[3]) / (float)N;
}

extern "C" void kernel_launch(void* const* d_in, const int* in_sizes, int n_in,
                              void* d_out, int out_size, void* d_ws, size_t ws_size,
                              hipStream_t stream){
    const float* f  = (const float*)d_in[0];
    const int*   nc = (const int*)d_in[1];
    int N = in_sizes[0] / 128;   // 8192
    int G = in_sizes[1];         // 2048

    unsigned int* zb = (unsigned int*)d_ws;                       // N*256 bytes bf16 z
    float* t     = (float*)((char*)d_ws + (size_t)N * 256);       // N fp32
    float* pos   = t + N;
    float* selfs = pos + N;
    int*   offs  = (int*)(selfs + N);                             // G ints
    float* out   = (float*)d_out;

    k_normalize<<<N / 4, 256, 0, stream>>>(f, zb, t, N);
    k_offsets<<<1, 64, 0, stream>>>(nc, offs, G);
    k_pos<<<G, 64, 0, stream>>>(zb, nc, offs, pos, selfs, G);
    int waves = (N / 64) * (N / 512);
    k_gram<<<waves / 4, 256, 0, stream>>>((const unsigned short*)zb, t, N);
    k_final<<<1, 256, 0, stream>>>(t, pos, selfs, out, N);
}

// Round 3
// 113.331 us; speedup vs baseline: 1.1993x; 1.1993x over previous
//
#include <hip/hip_runtime.h>
#include <hip/hip_bf16.h>

typedef __attribute__((ext_vector_type(8))) short short8;   // 8 bf16 (4 VGPRs)
typedef __attribute__((ext_vector_type(4))) float float4v;  // 4 fp32 acc

#define C2EXP 2.8853900817779268f  /* 2*log2(e): exp(2s) = exp2(C2EXP*s), tau=0.5 */

__device__ __forceinline__ float bf16lo(unsigned int u){ return __uint_as_float((u & 0xFFFFu) << 16); }
__device__ __forceinline__ float bf16hi(unsigned int u){ return __uint_as_float(u & 0xFFFF0000u); }

// K1: row-normalize fp32 features (norm clamp @1e-8), cast bf16, pack 2/lane.
// Also zero t accumulator and out (ws/out are poisoned before every launch).
__global__ void k_normalize(const float* __restrict__ f, unsigned int* __restrict__ zb,
                            float* __restrict__ t, float* __restrict__ out, int N){
    int lane = threadIdx.x & 63;
    int row  = blockIdx.x * 4 + (threadIdx.x >> 6);
    int gid  = blockIdx.x * 256 + threadIdx.x;
    if (gid == 0) out[0] = 0.0f;
    if (gid < N) t[gid] = 0.0f;
    if (row >= N) return;
    const float2* fr = (const float2*)(f + (size_t)row * 128);
    float2 v = fr[lane];
    float ss = v.x * v.x + v.y * v.y;
    #pragma unroll
    for (int m = 1; m < 64; m <<= 1) ss += __shfl_xor(ss, m);
    float scale = 1.0f / fmaxf(sqrtf(ss), 1e-8f);
    __hip_bfloat16 h0 = __float2bfloat16(v.x * scale);
    __hip_bfloat16 h1 = __float2bfloat16(v.y * scale);
    unsigned short b0, b1;
    __builtin_memcpy(&b0, &h0, 2);
    __builtin_memcpy(&b1, &h1, 2);
    zb[row * 64 + lane] = (unsigned int)b0 | ((unsigned int)b1 << 16);
}

// K2: per-group (one wave per group): pos[i] = sum_{j in group, j!=i} exp(2*cos),
// self[i] = exp(2*z_i.z_i). Group start = strided sum of num_crops (general).
__global__ void k_pos(const unsigned int* __restrict__ zb, const int* __restrict__ nc,
                      float* __restrict__ possum, float* __restrict__ selfs, int G){
    int g = blockIdx.x, lane = threadIdx.x;
    int st = 0;
    for (int i = lane; i < g; i += 64) st += nc[i];
    #pragma unroll
    for (int m = 1; m < 64; m <<= 1) st += __shfl_xor(st, m);
    int c = nc[g];
    for (int a = 0; a < c; a++){
        unsigned int ua = zb[(st + a) * 64 + lane];
        float a0 = bf16lo(ua), a1 = bf16hi(ua);
        float pacc = 0.0f;
        for (int b = 0; b < c; b++){
            unsigned int ub = zb[(st + b) * 64 + lane];
            float s = a0 * bf16lo(ub) + a1 * bf16hi(ub);
            #pragma unroll
            for (int m = 1; m < 64; m <<= 1) s += __shfl_xor(s, m);
            float e = exp2f(C2EXP * s);
            if (b == a){ if (lane == 0) selfs[st + a] = e; }
            else pacc += e;
        }
        if (lane == 0) possum[st + a] = pacc;
    }
}

// K3: barrier-free Gram row-sums, software-pipelined.
// Wave = 64 rows (A in registers, full K) x 512 cols streamed as 8 j-tiles of 64.
// Per tile: hi-K B-loads issue at top (covered by lo-K MFMAs); next tile's lo-K
// B-loads issue BEFORE the ~770-cyc exp epilogue, which hides their L2 latency.
// No LDS, no __syncthreads. Fragment: lane holds z[base+(lane&15)][ki*32+(lane>>4)*8..+7]
__global__ __launch_bounds__(256) void k_gram(const unsigned short* __restrict__ z,
                                              float* __restrict__ t, int N){
    int tid  = threadIdx.x;
    int lane = tid & 63;
    int w    = blockIdx.x * 4 + (tid >> 6);   // global wave id
    int quad = lane >> 4, l15 = lane & 15;
    int chunks = N >> 9;                      // col-chunks of 512
    int rs = w / chunks;                      // 64-row slab index
    int cc = w % chunks;
    size_t lq = (size_t)l15 * 128 + quad * 8; // per-lane fragment offset within a 16-row group

    // A fragments: 64 rows x full K=128, held for the whole kernel (16 x 16B loads)
    short8 af[4][4];
    #pragma unroll
    for (int mi = 0; mi < 4; mi++)
        #pragma unroll
        for (int ki = 0; ki < 4; ki++)
            af[mi][ki] = *(const short8*)&z[(size_t)(rs * 64 + mi * 16) * 128 + lq + ki * 32];

    float ts[4][4];
    #pragma unroll
    for (int mi = 0; mi < 4; mi++)
        #pragma unroll
        for (int r = 0; r < 4; r++) ts[mi][r] = 0.0f;

    int jbase = cc * 512;
    short8 bl[2][4], bh[2][4];
    // prologue: lo-K half (ki=0,1) of tile 0
    #pragma unroll
    for (int kk = 0; kk < 2; kk++)
        #pragma unroll
        for (int ni = 0; ni < 4; ni++)
            bl[kk][ni] = *(const short8*)&z[(size_t)(jbase + ni * 16) * 128 + lq + kk * 32];

    #pragma unroll 1
    for (int jt = 0; jt < 8; jt++){
        int j0 = jbase + jt * 64;
        // hi-K half (ki=2,3) of current tile — covered by lo-K MFMAs below
        #pragma unroll
        for (int kk = 0; kk < 2; kk++)
            #pragma unroll
            for (int ni = 0; ni < 4; ni++)
                bh[kk][ni] = *(const short8*)&z[(size_t)(j0 + ni * 16) * 128 + lq + (kk + 2) * 32];

        float4v acc[4][4];
        #pragma unroll
        for (int mi = 0; mi < 4; mi++)
            #pragma unroll
            for (int ni = 0; ni < 4; ni++)
                acc[mi][ni] = (float4v){0.0f, 0.0f, 0.0f, 0.0f};

        #pragma unroll
        for (int kk = 0; kk < 2; kk++)
            #pragma unroll
            for (int mi = 0; mi < 4; mi++)
                #pragma unroll
                for (int ni = 0; ni < 4; ni++)
                    acc[mi][ni] = __builtin_amdgcn_mfma_f32_16x16x32_bf16(
                        af[mi][kk], bl[kk][ni], acc[mi][ni], 0, 0, 0);
        #pragma unroll
        for (int kk = 0; kk < 2; kk++)
            #pragma unroll
            for (int mi = 0; mi < 4; mi++)
                #pragma unroll
                for (int ni = 0; ni < 4; ni++)
                    acc[mi][ni] = __builtin_amdgcn_mfma_f32_16x16x32_bf16(
                        af[mi][kk + 2], bh[kk][ni], acc[mi][ni], 0, 0, 0);

        // prefetch lo-K half of NEXT tile; its latency is hidden by the epilogue
        if (jt < 7){
            #pragma unroll
            for (int kk = 0; kk < 2; kk++)
                #pragma unroll
                for (int ni = 0; ni < 4; ni++)
                    bl[kk][ni] = *(const short8*)&z[(size_t)(j0 + 64 + ni * 16) * 128 + lq + kk * 32];
        }

        // epilogue: e = exp(2s), accumulate row partials.
        // C layout: col = lane&15, row_local = mi*16 + quad*4 + r
        #pragma unroll
        for (int mi = 0; mi < 4; mi++)
            #pragma unroll
            for (int ni = 0; ni < 4; ni++)
                #pragma unroll
                for (int r = 0; r < 4; r++)
                    ts[mi][r] += exp2f(C2EXP * acc[mi][ni][r]);
    }

    // Reduce across the 16 column-lanes (same quad), one atomic per row
    #pragma unroll
    for (int mi = 0; mi < 4; mi++)
        #pragma unroll
        for (int r = 0; r < 4; r++){
            float v = ts[mi][r];
            v += __shfl_xor(v, 1);
            v += __shfl_xor(v, 2);
            v += __shfl_xor(v, 4);
            v += __shfl_xor(v, 8);
            ts[mi][r] = v;
        }
    if (l15 == 0){
        #pragma unroll
        for (int mi = 0; mi < 4; mi++)
            #pragma unroll
            for (int r = 0; r < 4; r++){
                int i = rs * 64 + mi * 16 + quad * 4 + r;
                atomicAdd(&t[i], ts[mi][r]);
            }
    }
}

// K4: loss = mean over rows of log(neg) - log(pos); neg = t - pos - self.
// Parallel: 32 blocks, per-block reduce, one atomicAdd into pre-zeroed out.
__global__ void k_final(const float* __restrict__ t, const float* __restrict__ possum,
                        const float* __restrict__ selfs, float* __restrict__ out, int N){
    int tid = threadIdx.x;
    int gid = blockIdx.x * 256 + tid;
    float s = 0.0f;
    if (gid < N){
        float p = possum[gid];
        float n = t[gid] - p - selfs[gid];
        s = logf(n) - logf(p);
    }
    #pragma unroll
    for (int m = 1; m < 64; m <<= 1) s += __shfl_xor(s, m);
    __shared__ float red[4];
    if ((tid & 63) == 0) red[tid >> 6] = s;
    __syncthreads();
    if (tid == 0) atomicAdd(out, (red[0] + red[1] + red[2] + red[3]) / (float)N);
}

extern "C" void kernel_launch(void* const* d_in, const int* in_sizes, int n_in,
                              void* d_out, int out_size, void* d_ws, size_t ws_size,
                              hipStream_t stream){
    const float* f  = (const float*)d_in[0];
    const int*   nc = (const int*)d_in[1];
    int N = in_sizes[0] / 128;   // 8192
    int G = in_sizes[1];         // 2048

    unsigned int* zb = (unsigned int*)d_ws;                       // N*256 bytes bf16 z
    float* t     = (float*)((char*)d_ws + (size_t)N * 256);       // N fp32
    float* pos   = t + N;
    float* selfs = pos + N;
    float* out   = (float*)d_out;

    k_normalize<<<N / 4, 256, 0, stream>>>(f, zb, t, out, N);
    k_pos<<<G, 64, 0, stream>>>(zb, nc, pos, selfs, G);
    int waves = (N / 64) * (N / 512);
    k_gram<<<waves / 4, 256, 0, stream>>>((const unsigned short*)zb, t, N);
    k_final<<<(N + 255) / 256, 256, 0, stream>>>(t, pos, selfs, out, N);
}